// Round 16
// baseline (171.857 us; speedup 1.0000x reference)
//
#include <hip/hip_runtime.h>
#include <hip/hip_fp16.h>

// GCN encoder: out = A @ ( relu(A @ (X W1)) W2 ),  A = COO scatter (dst <- src)
// N=100000 nodes, E=1600000 edges, F_IN=128, H1=64, H2=32, all f32.
//
// Round 16: pass1's W1 staged in LDS as fp16 (32KB -> 16KB static LDS): LDS
// occupancy cap 5 -> 10 blocks/CU for both fused roles (gemm + binning).
// f32 accumulate kept (convert on read). Everything else = round 13/15.

constexpr int N_NODES = 100000;
constexpr int N_EDGES = 1600000;
constexpr int F_IN = 128;
constexpr int H1 = 64;
constexpr int H2 = 32;
constexpr int BSHIFT = 9;                         // 512 nodes per bucket
constexpr int BNODES = 1 << BSHIFT;
constexpr int NBUCK = (N_NODES + BNODES - 1) / BNODES;  // 196
constexpr int CAP = 10240;                        // per-bucket capacity
constexpr int CHUNK = 8192;                       // edges per binning workgroup
constexpr int P1_WGS = (N_EDGES + CHUNK - 1) / CHUNK;  // 196
constexpr int GEMM_WGS = (N_NODES + 255) / 256;        // 391

// ---------------- cursor init: cursor[b] = b*CAP ---------------------------
__global__ __launch_bounds__(256) void init_cursors(int* __restrict__ cursor)
{
    int t = threadIdx.x;
    if (t < NBUCK) cursor[t] = t * CAP;
}

// ---- pass1: gemm1 blocks first, then binning blocks -----------------------
// staging record: .x = src | (dst_low9 << 17)   (src < 2^17), .y = w bits
__global__ __launch_bounds__(256) void pass1_bin_gemm1(
    const int* __restrict__ src, const int* __restrict__ dst,
    const float* __restrict__ w, int* __restrict__ cursor,
    int2* __restrict__ staging,
    const float* __restrict__ X, const float* __restrict__ W1,
    __half* __restrict__ xw1out)
{
    __shared__ __half smem[F_IN * H1];               // 16 KiB (both roles)

    if (blockIdx.x < GEMM_WGS) {
        // ---------------- gemm_xw1 role (fp16 W1 in LDS, f32 accum) --------
        for (int i = threadIdx.x; i < F_IN * H1; i += 256)
            smem[i] = __float2half(W1[i]);
        __syncthreads();
        int row = blockIdx.x * 256 + threadIdx.x;
        if (row >= N_NODES) return;
        const float4* xr = reinterpret_cast<const float4*>(X + (size_t)row * F_IN);
        float4 acc[H1 / 4];
#pragma unroll
        for (int j = 0; j < H1 / 4; ++j) acc[j] = make_float4(0.f, 0.f, 0.f, 0.f);
        for (int k4 = 0; k4 < F_IN / 4; ++k4) {
            float4 xv = xr[k4];
#pragma unroll
            for (int kk = 0; kk < 4; ++kk) {
                float xk = (kk == 0) ? xv.x : (kk == 1) ? xv.y
                         : (kk == 2) ? xv.z : xv.w;
                const __half2* wr = reinterpret_cast<const __half2*>(
                    &smem[(k4 * 4 + kk) * H1]);
#pragma unroll
                for (int j = 0; j < H1 / 4; ++j) {
                    float2 w01 = __half22float2(wr[j * 2 + 0]);
                    float2 w23 = __half22float2(wr[j * 2 + 1]);
                    acc[j].x += xk * w01.x;
                    acc[j].y += xk * w01.y;
                    acc[j].z += xk * w23.x;
                    acc[j].w += xk * w23.y;
                }
            }
        }
        __half2* oh = reinterpret_cast<__half2*>(xw1out + (size_t)row * H1);
#pragma unroll
        for (int j = 0; j < H1 / 4; ++j) {
            oh[j * 2 + 0] = __floats2half2_rn(acc[j].x, acc[j].y);
            oh[j * 2 + 1] = __floats2half2_rn(acc[j].z, acc[j].w);
        }
        return;
    }

    // ---------------- binning role (32 edges/thread, 2 batches) ------------
    int* lcnt  = (int*)smem;        // [256] counters, then reused as cursors
    int* lbase = lcnt + 256;        // [256] reserved global bases

    int e0 = (blockIdx.x - GEMM_WGS) * CHUNK;
    int nhere = N_EDGES - e0; if (nhere > CHUNK) nhere = CHUNK;  // 8192 or 2560

    lcnt[threadIdx.x] = 0;
    __syncthreads();

    // batch A: edges e0 + t*16 (kept in registers through the barrier)
    int   esA[16]; int edA[16]; float ewA[16];
    {
        bool v = (threadIdx.x * 16) < nhere;
        int tb = e0 + threadIdx.x * 16;
        if (v) {
            const int4* sp = reinterpret_cast<const int4*>(src + tb);
            const int4* dp = reinterpret_cast<const int4*>(dst + tb);
            const float4* wp = reinterpret_cast<const float4*>(w + tb);
#pragma unroll
            for (int q = 0; q < 4; ++q) {
                int4 sv = sp[q], dv = dp[q]; float4 wv = wp[q];
                esA[4*q+0]=sv.x; esA[4*q+1]=sv.y; esA[4*q+2]=sv.z; esA[4*q+3]=sv.w;
                edA[4*q+0]=dv.x; edA[4*q+1]=dv.y; edA[4*q+2]=dv.z; edA[4*q+3]=dv.w;
                ewA[4*q+0]=wv.x; ewA[4*q+1]=wv.y; ewA[4*q+2]=wv.z; ewA[4*q+3]=wv.w;
            }
        } else {
#pragma unroll
            for (int k = 0; k < 16; ++k) { esA[k]=0; edA[k]=-1; ewA[k]=0.f; }
        }
    }
#pragma unroll
    for (int k = 0; k < 16; ++k)
        if (edA[k] >= 0) atomicAdd(&lcnt[edA[k] >> BSHIFT], 1);

    // batch B: edges e0 + 4096 + t*16 (hist only; reloaded later)
    {
        int ob = 4096 + threadIdx.x * 16;
        if (ob < nhere) {
            const int4* dp = reinterpret_cast<const int4*>(dst + e0 + ob);
#pragma unroll
            for (int q = 0; q < 4; ++q) {
                int4 dv = dp[q];
                atomicAdd(&lcnt[dv.x >> BSHIFT], 1);
                atomicAdd(&lcnt[dv.y >> BSHIFT], 1);
                atomicAdd(&lcnt[dv.z >> BSHIFT], 1);
                atomicAdd(&lcnt[dv.w >> BSHIFT], 1);
            }
        }
    }
    __syncthreads();
    if (threadIdx.x < NBUCK) {
        int c = lcnt[threadIdx.x];
        lbase[threadIdx.x] = (c > 0) ? atomicAdd(&cursor[threadIdx.x], c) : 0;
    }
    __syncthreads();
    lcnt[threadIdx.x] = 0;                            // reuse as cursors
    __syncthreads();
    // scatter batch A from registers
#pragma unroll
    for (int k = 0; k < 16; ++k) {
        if (edA[k] >= 0) {
            int b = edA[k] >> BSHIFT;
            int r = atomicAdd(&lcnt[b], 1);
            int pos = lbase[b] + r;
            if (pos < (b + 1) * CAP)                  // capacity guard
                staging[pos] = make_int2(
                    esA[k] | ((edA[k] & (BNODES - 1)) << 17),
                    __float_as_int(ewA[k]));
        }
    }
    // reload + scatter batch B
    {
        int ob = 4096 + threadIdx.x * 16;
        if (ob < nhere) {
            int tb = e0 + ob;
            const int4* sp = reinterpret_cast<const int4*>(src + tb);
            const int4* dp = reinterpret_cast<const int4*>(dst + tb);
            const float4* wp = reinterpret_cast<const float4*>(w + tb);
#pragma unroll
            for (int q = 0; q < 4; ++q) {
                int4 sv = sp[q], dv = dp[q]; float4 wv = wp[q];
                int   es4[4] = {sv.x, sv.y, sv.z, sv.w};
                int   ed4[4] = {dv.x, dv.y, dv.z, dv.w};
                float ew4[4] = {wv.x, wv.y, wv.z, wv.w};
#pragma unroll
                for (int k = 0; k < 4; ++k) {
                    int b = ed4[k] >> BSHIFT;
                    int r = atomicAdd(&lcnt[b], 1);
                    int pos = lbase[b] + r;
                    if (pos < (b + 1) * CAP)
                        staging[pos] = make_int2(
                            es4[k] | ((ed4[k] & (BNODES - 1)) << 17),
                            __float_as_int(ew4[k]));
                }
            }
        }
    }
}

// ---- sort_bucket: LDS counting sort -> csr + seg (4-aligned, 0-padded) ----
__global__ __launch_bounds__(1024) void sort_bucket(
    const int* __restrict__ cursor, const int2* __restrict__ staging,
    int2* __restrict__ csr, int2* __restrict__ seg)
{
    __shared__ int  lcnt[BNODES];                    // 2 KiB
    __shared__ int  lofs[BNODES];                    // 2 KiB
    __shared__ int2 sorted[CAP];                     // 80 KiB
    __shared__ int  total_sh;

    int b = blockIdx.x, t = threadIdx.x;
    int base = b * CAP;
    int cnt = cursor[b] - base; if (cnt > CAP) cnt = CAP;

    if (t < BNODES) lcnt[t] = 0;
    __syncthreads();

    for (int j = t; j < cnt; j += 1024)
        atomicAdd(&lcnt[(staging[base + j].x >> 17) & (BNODES - 1)], 1);
    __syncthreads();

    int v = (t < BNODES) ? lcnt[t] : 0;              // true count
    int pc = (v + 3) & ~3;                           // padded to multiple of 4
    if (t < BNODES) lofs[t] = pc;
    __syncthreads();
    for (int off = 1; off < BNODES; off <<= 1) {
        int add = (t >= off && t < BNODES) ? lofs[t - off] : 0;
        __syncthreads();
        if (t < BNODES) lofs[t] += add;
        __syncthreads();
    }
    if (t < BNODES) {
        int pexcl = lofs[t] - pc;                    // padded exclusive prefix
        seg[b * BNODES + t] = make_int2(base + pexcl, pc);
        lcnt[t] = pexcl;                             // running scatter cursors
        for (int j = v; j < pc; ++j)                 // zero-weight padding
            if (pexcl + j < CAP) sorted[pexcl + j] = make_int2(0, 0);
        if (t == BNODES - 1) {
            int tot = lofs[t]; if (tot > CAP) tot = CAP;
            total_sh = tot;
        }
    }
    __syncthreads();

    for (int j = t; j < cnt; j += 1024) {
        int2 c = staging[base + j];
        int node = (c.x >> 17) & (BNODES - 1);
        int pos = atomicAdd(&lcnt[node], 1);
        if (pos < CAP) sorted[pos] = make_int2(c.x & 0x1FFFF, c.y);
    }
    __syncthreads();

    int total = total_sh;
    for (int j = t; j < total; j += 1024) csr[base + j] = sorted[j];
}

// ---- layer1 SpMM + fused relu + W2: one wave per node (r13 form) ----------
__global__ __launch_bounds__(256) void spmm1_fused(
    const int2* __restrict__ seg, const int2* __restrict__ csr,
    const __half* __restrict__ xin, const float* __restrict__ W2,
    __half* __restrict__ h1w2h)
{
    int gid = blockIdx.x * 256 + threadIdx.x;        // grid covers N*64 exactly
    int node = __builtin_amdgcn_readfirstlane(gid >> 6);
    int f = gid & 63;
    int par = f >> 5;                                // edge parity
    int f2 = f & 31;                                 // feature pair: 2f2, 2f2+1

    // preload W2[par*32 .. +31][f2] into registers (cache-resident)
    float w2r[32];
#pragma unroll
    for (int kk = 0; kk < 32; ++kk)
        w2r[kk] = W2[(par * 32 + kk) * H2 + f2];

    int2 s = seg[node];
    int start = __builtin_amdgcn_readfirstlane(s.x);
    int cntp  = __builtin_amdgcn_readfirstlane(s.y); // multiple of 4
    const int4* csr4 = reinterpret_cast<const int4*>(csr);

    float2 a0 = make_float2(0.f, 0.f), a1 = make_float2(0.f, 0.f);
    for (int e = start; e < start + cntp; e += 4) {  // 2 edges per parity
        int4 p0 = csr4[(e >> 1) + 0];                // entries e, e+1 (uniform)
        int4 p1 = csr4[(e >> 1) + 1];                // entries e+2, e+3
        int  sA = par ? p0.z : p0.x;
        float wA = __int_as_float(par ? p0.w : p0.y);
        int  sB = par ? p1.z : p1.x;
        float wB = __int_as_float(par ? p1.w : p1.y);
        float2 xA = __half22float2(
            *reinterpret_cast<const __half2*>(&xin[(size_t)sA * H1 + 2 * f2]));
        float2 xB = __half22float2(
            *reinterpret_cast<const __half2*>(&xin[(size_t)sB * H1 + 2 * f2]));
        a0.x += wA * xA.x; a0.y += wA * xA.y;
        a1.x += wB * xB.x; a1.y += wB * xB.y;
    }
    float rx = a0.x + a1.x, ry = a0.y + a1.y;
    rx += __shfl_xor(rx, 32, 64);                    // combine parities
    ry += __shfl_xor(ry, 32, 64);
    rx = fmaxf(rx, 0.f); ry = fmaxf(ry, 0.f);        // relu(h1) pair

    // o[j=f2] partial over k = par*32 + kk; pair p = 16*par + kk/2
    float o = 0.f;
#pragma unroll
    for (int kk = 0; kk < 32; kk += 2) {
        int p = 16 * par + (kk >> 1);
        o += __shfl(rx, p, 64) * w2r[kk];
        o += __shfl(ry, p, 64) * w2r[kk + 1];
    }
    o += __shfl_xor(o, 32, 64);
    if (f < 32)
        h1w2h[(size_t)node * H2 + f2] = __float2half(o);
}

// ---- layer 2 SpMM: wave per node, quarter-waves on edge slots -------------
__global__ __launch_bounds__(256) void spmm_csr32h(
    const int2* __restrict__ seg, const int2* __restrict__ csr,
    const __half* __restrict__ xin, float* __restrict__ out)
{
    int gid = blockIdx.x * 256 + threadIdx.x;        // grid covers N*64 exactly
    int node = __builtin_amdgcn_readfirstlane(gid >> 6);
    int lane = gid & 63;
    int slot = lane >> 4;                            // edge slot 0..3
    int f2 = lane & 15;                              // feature pair: 2f2, 2f2+1

    int2 s = seg[node];
    int start = __builtin_amdgcn_readfirstlane(s.x);
    int cntp  = __builtin_amdgcn_readfirstlane(s.y); // multiple of 4
    int endp = start + cntp;
    const int4* csr4 = reinterpret_cast<const int4*>(csr);

    float2 a0 = make_float2(0.f, 0.f), a1 = make_float2(0.f, 0.f);
    int e = start;
    for (; e + 8 <= endp; e += 8) {                  // 2 edges per slot
        int4 q0 = csr4[(e >> 1) + 0];
        int4 q1 = csr4[(e >> 1) + 1];
        int4 q2 = csr4[(e >> 1) + 2];
        int4 q3 = csr4[(e >> 1) + 3];
        int4 qa = (slot & 2) ? q1 : q0;
        int  sA = (slot & 1) ? qa.z : qa.x;
        float wA = __int_as_float((slot & 1) ? qa.w : qa.y);
        int4 qb = (slot & 2) ? q3 : q2;
        int  sB = (slot & 1) ? qb.z : qb.x;
        float wB = __int_as_float((slot & 1) ? qb.w : qb.y);
        float2 xA = __half22float2(
            *reinterpret_cast<const __half2*>(&xin[(size_t)sA * H2 + 2 * f2]));
        float2 xB = __half22float2(
            *reinterpret_cast<const __half2*>(&xin[(size_t)sB * H2 + 2 * f2]));
        a0.x += wA * xA.x; a0.y += wA * xA.y;
        a1.x += wB * xB.x; a1.y += wB * xB.y;
    }
    if (e < endp) {                                  // one 4-group tail
        int4 q0 = csr4[(e >> 1) + 0];
        int4 q1 = csr4[(e >> 1) + 1];
        int4 qa = (slot & 2) ? q1 : q0;
        int  sA = (slot & 1) ? qa.z : qa.x;
        float wA = __int_as_float((slot & 1) ? qa.w : qa.y);
        float2 xA = __half22float2(
            *reinterpret_cast<const __half2*>(&xin[(size_t)sA * H2 + 2 * f2]));
        a0.x += wA * xA.x; a0.y += wA * xA.y;
    }
    float ox = a0.x + a1.x, oy = a0.y + a1.y;
    ox += __shfl_xor(ox, 16, 64); oy += __shfl_xor(oy, 16, 64);
    ox += __shfl_xor(ox, 32, 64); oy += __shfl_xor(oy, 32, 64);
    if (lane < 16)
        *reinterpret_cast<float2*>(&out[(size_t)node * H2 + 2 * f2]) =
            make_float2(ox, oy);
}

extern "C" void kernel_launch(void* const* d_in, const int* in_sizes, int n_in,
                              void* d_out, int out_size, void* d_ws, size_t ws_size,
                              hipStream_t stream)
{
    const float* features    = (const float*)d_in[0];   // [N, 128]
    const float* edge_weight = (const float*)d_in[1];   // [E]
    const float* W1          = (const float*)d_in[2];   // [128, 64]
    const float* W2          = (const float*)d_in[3];   // [64, 32]
    const int*   src         = (const int*)d_in[4];     // [E]
    const int*   dst         = (const int*)d_in[5];     // [E]
    float* out = (float*)d_out;                          // [N, 32]

    // workspace layout (~52 MB)
    char* p = (char*)d_ws;
    __half* xw1h   = (__half*)p;    p += (size_t)N_NODES * H1 * 2;        // 12.8MB
    __half* h1w2h  = (__half*)p;    p += (size_t)N_NODES * H2 * 2;        // 6.4MB
    int2*  staging = (int2*)p;      p += (size_t)NBUCK * CAP * 8;         // 16.06MB
    int2*  csr     = (int2*)p;      p += (size_t)NBUCK * CAP * 8;         // 16.06MB
    int2*  seg     = (int2*)p;      p += (size_t)NBUCK * BNODES * 8;      // 0.80MB
    int*   cursor  = (int*)p;       p += 256 * 4;

    init_cursors<<<1, 256, 0, stream>>>(cursor);
    pass1_bin_gemm1<<<P1_WGS + GEMM_WGS, 256, 0, stream>>>(
        src, dst, edge_weight, cursor, staging, features, W1, xw1h);
    sort_bucket<<<NBUCK, 1024, 0, stream>>>(cursor, staging, csr, seg);

    spmm1_fused<<<(N_NODES * 64) / 256, 256, 0, stream>>>(seg, csr, xw1h, W2, h1w2h);
    spmm_csr32h<<<(N_NODES * 64) / 256, 256, 0, stream>>>(seg, csr, h1w2h, out);
}

// Round 17
// 158.549 us; speedup vs baseline: 1.0839x; 1.0839x over previous
//
#include <hip/hip_runtime.h>
#include <hip/hip_fp16.h>

// GCN encoder: out = A @ ( relu(A @ (X W1)) W2 ),  A = COO scatter (dst <- src)
// N=100000 nodes, E=1600000 edges, F_IN=128, H1=64, H2=32, all f32.
//
// Round 17: r13 base (best known: 158us) + (a) software-pipelined uniform csr
// loads in both spmm kernels (prefetch iter i+1's scalar int4s during iter i's
// gathers), (b) cursor stores within-bucket offsets so init is a memset (one
// kernel launch removed). pass1/sort identical to r13.

constexpr int N_NODES = 100000;
constexpr int N_EDGES = 1600000;
constexpr int F_IN = 128;
constexpr int H1 = 64;
constexpr int H2 = 32;
constexpr int BSHIFT = 9;                         // 512 nodes per bucket
constexpr int BNODES = 1 << BSHIFT;
constexpr int NBUCK = (N_NODES + BNODES - 1) / BNODES;  // 196
constexpr int CAP = 10240;                        // per-bucket capacity
constexpr int CHUNK = 4096;                       // edges per binning workgroup
constexpr int P1_WGS = (N_EDGES + CHUNK - 1) / CHUNK;  // 391
constexpr int GEMM_WGS = (N_NODES + 255) / 256;        // 391

// ---- pass1: gemm1 blocks first, then binning blocks -----------------------
// staging record: .x = src | (dst_low9 << 17)   (src < 2^17), .y = w bits
// cursor[b] holds the within-bucket fill offset (init = 0 via memset).
__global__ __launch_bounds__(256) void pass1_bin_gemm1(
    const int* __restrict__ src, const int* __restrict__ dst,
    const float* __restrict__ w, int* __restrict__ cursor,
    int2* __restrict__ staging,
    const float* __restrict__ X, const float* __restrict__ W1,
    __half* __restrict__ xw1out)
{
    __shared__ float smem[F_IN * H1];                // 32 KiB (both roles)

    if (blockIdx.x < GEMM_WGS) {
        // ---------------- gemm_xw1 role ----------------
        for (int i = threadIdx.x; i < F_IN * H1; i += 256) smem[i] = W1[i];
        __syncthreads();
        int row = blockIdx.x * 256 + threadIdx.x;
        if (row >= N_NODES) return;
        const float4* xr = reinterpret_cast<const float4*>(X + (size_t)row * F_IN);
        float4 acc[H1 / 4];
#pragma unroll
        for (int j = 0; j < H1 / 4; ++j) acc[j] = make_float4(0.f, 0.f, 0.f, 0.f);
        for (int k4 = 0; k4 < F_IN / 4; ++k4) {
            float4 xv = xr[k4];
#pragma unroll
            for (int kk = 0; kk < 4; ++kk) {
                float xk = (kk == 0) ? xv.x : (kk == 1) ? xv.y
                         : (kk == 2) ? xv.z : xv.w;
                const float4* wr = reinterpret_cast<const float4*>(
                    &smem[(k4 * 4 + kk) * H1]);
#pragma unroll
                for (int j = 0; j < H1 / 4; ++j) {
                    float4 wv = wr[j];
                    acc[j].x += xk * wv.x;
                    acc[j].y += xk * wv.y;
                    acc[j].z += xk * wv.z;
                    acc[j].w += xk * wv.w;
                }
            }
        }
        __half2* oh = reinterpret_cast<__half2*>(xw1out + (size_t)row * H1);
#pragma unroll
        for (int j = 0; j < H1 / 4; ++j) {
            oh[j * 2 + 0] = __floats2half2_rn(acc[j].x, acc[j].y);
            oh[j * 2 + 1] = __floats2half2_rn(acc[j].z, acc[j].w);
        }
        return;
    }

    // ---------------- binning role (16 edges per thread) ----------------
    int* lcnt  = (int*)smem;        // [256] counters, then reused as cursors
    int* lbase = lcnt + 256;        // [256] reserved in-bucket bases

    int e0 = (blockIdx.x - GEMM_WGS) * CHUNK;
    int nhere = N_EDGES - e0; if (nhere > CHUNK) nhere = CHUNK;  // 4096 or 2560

    lcnt[threadIdx.x] = 0;
    __syncthreads();

    int   es[16];
    int   ed[16];
    float ew[16];
    {
        bool v = (threadIdx.x * 16) < nhere;         // nhere % 16 == 0
        int tb = e0 + threadIdx.x * 16;
        if (v) {
            const int4* sp = reinterpret_cast<const int4*>(src + tb);
            const int4* dp = reinterpret_cast<const int4*>(dst + tb);
            const float4* wp = reinterpret_cast<const float4*>(w + tb);
#pragma unroll
            for (int q = 0; q < 4; ++q) {
                int4 sv = sp[q], dv = dp[q]; float4 wv = wp[q];
                es[4*q+0]=sv.x; es[4*q+1]=sv.y; es[4*q+2]=sv.z; es[4*q+3]=sv.w;
                ed[4*q+0]=dv.x; ed[4*q+1]=dv.y; ed[4*q+2]=dv.z; ed[4*q+3]=dv.w;
                ew[4*q+0]=wv.x; ew[4*q+1]=wv.y; ew[4*q+2]=wv.z; ew[4*q+3]=wv.w;
            }
        } else {
#pragma unroll
            for (int k = 0; k < 16; ++k) { es[k]=0; ed[k]=-1; ew[k]=0.f; }
        }
    }
#pragma unroll
    for (int k = 0; k < 16; ++k)
        if (ed[k] >= 0) atomicAdd(&lcnt[ed[k] >> BSHIFT], 1);
    __syncthreads();
    if (threadIdx.x < NBUCK) {
        int c = lcnt[threadIdx.x];
        lbase[threadIdx.x] = (c > 0) ? atomicAdd(&cursor[threadIdx.x], c) : 0;
    }
    __syncthreads();
    lcnt[threadIdx.x] = 0;                            // reuse as cursors
    __syncthreads();
#pragma unroll
    for (int k = 0; k < 16; ++k) {
        if (ed[k] >= 0) {
            int b = ed[k] >> BSHIFT;
            int r = atomicAdd(&lcnt[b], 1);
            int off = lbase[b] + r;
            if (off < CAP)                            // capacity guard
                staging[b * CAP + off] = make_int2(
                    es[k] | ((ed[k] & (BNODES - 1)) << 17),
                    __float_as_int(ew[k]));
        }
    }
}

// ---- sort_bucket: LDS counting sort -> csr + seg (4-aligned, 0-padded) ----
__global__ __launch_bounds__(1024) void sort_bucket(
    const int* __restrict__ cursor, const int2* __restrict__ staging,
    int2* __restrict__ csr, int2* __restrict__ seg)
{
    __shared__ int  lcnt[BNODES];                    // 2 KiB
    __shared__ int  lofs[BNODES];                    // 2 KiB
    __shared__ int2 sorted[CAP];                     // 80 KiB
    __shared__ int  total_sh;

    int b = blockIdx.x, t = threadIdx.x;
    int base = b * CAP;
    int cnt = cursor[b]; if (cnt > CAP) cnt = CAP;   // count (offset semantics)

    if (t < BNODES) lcnt[t] = 0;
    __syncthreads();

    for (int j = t; j < cnt; j += 1024)
        atomicAdd(&lcnt[(staging[base + j].x >> 17) & (BNODES - 1)], 1);
    __syncthreads();

    int v = (t < BNODES) ? lcnt[t] : 0;              // true count
    int pc = (v + 3) & ~3;                           // padded to multiple of 4
    if (t < BNODES) lofs[t] = pc;
    __syncthreads();
    for (int off = 1; off < BNODES; off <<= 1) {
        int add = (t >= off && t < BNODES) ? lofs[t - off] : 0;
        __syncthreads();
        if (t < BNODES) lofs[t] += add;
        __syncthreads();
    }
    if (t < BNODES) {
        int pexcl = lofs[t] - pc;                    // padded exclusive prefix
        seg[b * BNODES + t] = make_int2(base + pexcl, pc);
        lcnt[t] = pexcl;                             // running scatter cursors
        for (int j = v; j < pc; ++j)                 // zero-weight padding
            if (pexcl + j < CAP) sorted[pexcl + j] = make_int2(0, 0);
        if (t == BNODES - 1) {
            int tot = lofs[t]; if (tot > CAP) tot = CAP;
            total_sh = tot;
        }
    }
    __syncthreads();

    for (int j = t; j < cnt; j += 1024) {
        int2 c = staging[base + j];
        int node = (c.x >> 17) & (BNODES - 1);
        int pos = atomicAdd(&lcnt[node], 1);
        if (pos < CAP) sorted[pos] = make_int2(c.x & 0x1FFFF, c.y);
    }
    __syncthreads();

    int total = total_sh;
    for (int j = t; j < total; j += 1024) csr[base + j] = sorted[j];
}

// ---- layer1 SpMM + fused relu + W2: one wave per node, pipelined csr ------
__global__ __launch_bounds__(256) void spmm1_fused(
    const int2* __restrict__ seg, const int2* __restrict__ csr,
    const __half* __restrict__ xin, const float* __restrict__ W2,
    __half* __restrict__ h1w2h)
{
    int gid = blockIdx.x * 256 + threadIdx.x;        // grid covers N*64 exactly
    int node = __builtin_amdgcn_readfirstlane(gid >> 6);
    int f = gid & 63;
    int par = f >> 5;                                // edge parity
    int f2 = f & 31;                                 // feature pair: 2f2, 2f2+1

    // preload W2[par*32 .. +31][f2] into registers (cache-resident)
    float w2r[32];
#pragma unroll
    for (int kk = 0; kk < 32; ++kk)
        w2r[kk] = W2[(par * 32 + kk) * H2 + f2];

    int2 s = seg[node];
    int start = __builtin_amdgcn_readfirstlane(s.x);
    int cntp  = __builtin_amdgcn_readfirstlane(s.y); // multiple of 4
    const int4* csr4 = reinterpret_cast<const int4*>(csr);
    int iters = cntp >> 2;

    float2 a0 = make_float2(0.f, 0.f), a1 = make_float2(0.f, 0.f);
    // software pipeline: csr words for iter i+1 prefetched during iter i.
    // Over-read past segment end stays inside the csr/ws allocation (unused).
    int4 p0 = csr4[(start >> 1) + 0];
    int4 p1 = csr4[(start >> 1) + 1];
    for (int i = 0; i < iters; ++i) {
        int nb = (start >> 1) + (i + 1) * 2;
        int4 n0 = csr4[nb + 0];
        int4 n1 = csr4[nb + 1];
        int  sA = par ? p0.z : p0.x;
        float wA = __int_as_float(par ? p0.w : p0.y);
        int  sB = par ? p1.z : p1.x;
        float wB = __int_as_float(par ? p1.w : p1.y);
        float2 xA = __half22float2(
            *reinterpret_cast<const __half2*>(&xin[(size_t)sA * H1 + 2 * f2]));
        float2 xB = __half22float2(
            *reinterpret_cast<const __half2*>(&xin[(size_t)sB * H1 + 2 * f2]));
        a0.x += wA * xA.x; a0.y += wA * xA.y;
        a1.x += wB * xB.x; a1.y += wB * xB.y;
        p0 = n0; p1 = n1;
    }
    float rx = a0.x + a1.x, ry = a0.y + a1.y;
    rx += __shfl_xor(rx, 32, 64);                    // combine parities
    ry += __shfl_xor(ry, 32, 64);
    rx = fmaxf(rx, 0.f); ry = fmaxf(ry, 0.f);        // relu(h1) pair

    // o[j=f2] partial over k = par*32 + kk; pair p = 16*par + kk/2
    float o = 0.f;
#pragma unroll
    for (int kk = 0; kk < 32; kk += 2) {
        int p = 16 * par + (kk >> 1);
        o += __shfl(rx, p, 64) * w2r[kk];
        o += __shfl(ry, p, 64) * w2r[kk + 1];
    }
    o += __shfl_xor(o, 32, 64);
    if (f < 32)
        h1w2h[(size_t)node * H2 + f2] = __float2half(o);
}

// ---- layer 2 SpMM: wave per node, quarter-wave slots, pipelined csr -------
__global__ __launch_bounds__(256) void spmm_csr32h(
    const int2* __restrict__ seg, const int2* __restrict__ csr,
    const __half* __restrict__ xin, float* __restrict__ out)
{
    int gid = blockIdx.x * 256 + threadIdx.x;        // grid covers N*64 exactly
    int node = __builtin_amdgcn_readfirstlane(gid >> 6);
    int lane = gid & 63;
    int slot = lane >> 4;                            // edge slot 0..3
    int f2 = lane & 15;                              // feature pair: 2f2, 2f2+1

    int2 s = seg[node];
    int start = __builtin_amdgcn_readfirstlane(s.x);
    int cntp  = __builtin_amdgcn_readfirstlane(s.y); // multiple of 4
    const int4* csr4 = reinterpret_cast<const int4*>(csr);

    float2 a0 = make_float2(0.f, 0.f), a1 = make_float2(0.f, 0.f);
    int full = cntp >> 3;                            // 8-edge iterations
    int sb = start >> 1;
    // prefetch first group
    int4 q0 = csr4[sb + 0], q1 = csr4[sb + 1];
    int4 q2 = csr4[sb + 2], q3 = csr4[sb + 3];
    for (int i = 0; i < full; ++i) {
        int nb = sb + (i + 1) * 4;
        int4 r0 = csr4[nb + 0], r1 = csr4[nb + 1];
        int4 r2 = csr4[nb + 2], r3 = csr4[nb + 3];
        int4 qa = (slot & 2) ? q1 : q0;
        int  sA = (slot & 1) ? qa.z : qa.x;
        float wA = __int_as_float((slot & 1) ? qa.w : qa.y);
        int4 qb = (slot & 2) ? q3 : q2;
        int  sB = (slot & 1) ? qb.z : qb.x;
        float wB = __int_as_float((slot & 1) ? qb.w : qb.y);
        float2 xA = __half22float2(
            *reinterpret_cast<const __half2*>(&xin[(size_t)sA * H2 + 2 * f2]));
        float2 xB = __half22float2(
            *reinterpret_cast<const __half2*>(&xin[(size_t)sB * H2 + 2 * f2]));
        a0.x += wA * xA.x; a0.y += wA * xA.y;
        a1.x += wB * xB.x; a1.y += wB * xB.y;
        q0 = r0; q1 = r1; q2 = r2; q3 = r3;
    }
    if (cntp & 4) {                                  // one 4-group tail
        int4 qa = (slot & 2) ? q1 : q0;              // q0,q1 already loaded
        int  sA = (slot & 1) ? qa.z : qa.x;
        float wA = __int_as_float((slot & 1) ? qa.w : qa.y);
        float2 xA = __half22float2(
            *reinterpret_cast<const __half2*>(&xin[(size_t)sA * H2 + 2 * f2]));
        a0.x += wA * xA.x; a0.y += wA * xA.y;
    }
    float ox = a0.x + a1.x, oy = a0.y + a1.y;
    ox += __shfl_xor(ox, 16, 64); oy += __shfl_xor(oy, 16, 64);
    ox += __shfl_xor(ox, 32, 64); oy += __shfl_xor(oy, 32, 64);
    if (lane < 16)
        *reinterpret_cast<float2*>(&out[(size_t)node * H2 + 2 * f2]) =
            make_float2(ox, oy);
}

extern "C" void kernel_launch(void* const* d_in, const int* in_sizes, int n_in,
                              void* d_out, int out_size, void* d_ws, size_t ws_size,
                              hipStream_t stream)
{
    const float* features    = (const float*)d_in[0];   // [N, 128]
    const float* edge_weight = (const float*)d_in[1];   // [E]
    const float* W1          = (const float*)d_in[2];   // [128, 64]
    const float* W2          = (const float*)d_in[3];   // [64, 32]
    const int*   src         = (const int*)d_in[4];     // [E]
    const int*   dst         = (const int*)d_in[5];     // [E]
    float* out = (float*)d_out;                          // [N, 32]

    // workspace layout (~52 MB)
    char* p = (char*)d_ws;
    __half* xw1h   = (__half*)p;    p += (size_t)N_NODES * H1 * 2;        // 12.8MB
    __half* h1w2h  = (__half*)p;    p += (size_t)N_NODES * H2 * 2;        // 6.4MB
    int2*  staging = (int2*)p;      p += (size_t)NBUCK * CAP * 8;         // 16.06MB
    int2*  csr     = (int2*)p;      p += (size_t)NBUCK * CAP * 8;         // 16.06MB
    int2*  seg     = (int2*)p;      p += (size_t)NBUCK * BNODES * 8;      // 0.80MB
    int*   cursor  = (int*)p;       p += 256 * 4;

    hipMemsetAsync(cursor, 0, 256 * 4, stream);      // cursor = in-bucket offsets
    pass1_bin_gemm1<<<P1_WGS + GEMM_WGS, 256, 0, stream>>>(
        src, dst, edge_weight, cursor, staging, features, W1, xw1h);
    sort_bucket<<<NBUCK, 1024, 0, stream>>>(cursor, staging, csr, seg);

    spmm1_fused<<<(N_NODES * 64) / 256, 256, 0, stream>>>(seg, csr, xw1h, W2, h1w2h);
    spmm_csr32h<<<(N_NODES * 64) / 256, 256, 0, stream>>>(seg, csr, h1w2h, out);
}

// Round 18
// 156.416 us; speedup vs baseline: 1.0987x; 1.0136x over previous
//
#include <hip/hip_runtime.h>
#include <hip/hip_fp16.h>

// GCN encoder: out = A @ ( relu(A @ (X W1)) W2 ),  A = COO scatter (dst <- src)
// N=100000 nodes, E=1600000 edges, F_IN=128, H1=64, H2=32, all f32.
//
// Round 18: binning role rewritten with software write-combining: edges are
// counting-sorted by bucket INSIDE LDS (hist -> scan -> LDS scatter into the
// 32KB buffer shared with gemm's W1), then streamed out coalesced (runs of
// ~21 records per bucket are contiguous in both LDS and staging). Kills the
// 3x dirty-line amplification (WRITE_SIZE 37MB for 12.8MB payload).
// Consumers / sort_bucket identical to round 17.

constexpr int N_NODES = 100000;
constexpr int N_EDGES = 1600000;
constexpr int F_IN = 128;
constexpr int H1 = 64;
constexpr int H2 = 32;
constexpr int BSHIFT = 9;                         // 512 nodes per bucket
constexpr int BNODES = 1 << BSHIFT;
constexpr int NBUCK = (N_NODES + BNODES - 1) / BNODES;  // 196
constexpr int CAP = 10240;                        // per-bucket capacity
constexpr int CHUNK = 4096;                       // edges per binning workgroup
constexpr int P1_WGS = (N_EDGES + CHUNK - 1) / CHUNK;  // 391
constexpr int GEMM_WGS = (N_NODES + 255) / 256;        // 391

// ---- pass1: gemm1 blocks first, then binning blocks -----------------------
// staging record: .x = src | (dst_low9 << 17)   (src < 2^17), .y = w bits
// cursor[b] holds the within-bucket fill offset (init = 0 via memset).
__global__ __launch_bounds__(256) void pass1_bin_gemm1(
    const int* __restrict__ src, const int* __restrict__ dst,
    const float* __restrict__ w, int* __restrict__ cursor,
    int2* __restrict__ staging,
    const float* __restrict__ X, const float* __restrict__ W1,
    __half* __restrict__ xw1out)
{
    __shared__ int2 bigbuf[CHUNK];                   // 32 KiB: W1 / sorted recs
    __shared__ int  lcnt[256];                       // hist, then scatter cursors
    __shared__ int  lexcl[256];                      // local exclusive offsets
    __shared__ int  lbase[256];                      // reserved in-bucket bases
    __shared__ unsigned char rid[CHUNK];             // 4 KiB bucket id / record

    if (blockIdx.x < GEMM_WGS) {
        // ---------------- gemm_xw1 role ----------------
        float* smem = (float*)bigbuf;                // [F_IN * H1]
        for (int i = threadIdx.x; i < F_IN * H1; i += 256) smem[i] = W1[i];
        __syncthreads();
        int row = blockIdx.x * 256 + threadIdx.x;
        if (row >= N_NODES) return;
        const float4* xr = reinterpret_cast<const float4*>(X + (size_t)row * F_IN);
        float4 acc[H1 / 4];
#pragma unroll
        for (int j = 0; j < H1 / 4; ++j) acc[j] = make_float4(0.f, 0.f, 0.f, 0.f);
        for (int k4 = 0; k4 < F_IN / 4; ++k4) {
            float4 xv = xr[k4];
#pragma unroll
            for (int kk = 0; kk < 4; ++kk) {
                float xk = (kk == 0) ? xv.x : (kk == 1) ? xv.y
                         : (kk == 2) ? xv.z : xv.w;
                const float4* wr = reinterpret_cast<const float4*>(
                    &smem[(k4 * 4 + kk) * H1]);
#pragma unroll
                for (int j = 0; j < H1 / 4; ++j) {
                    float4 wv = wr[j];
                    acc[j].x += xk * wv.x;
                    acc[j].y += xk * wv.y;
                    acc[j].z += xk * wv.z;
                    acc[j].w += xk * wv.w;
                }
            }
        }
        __half2* oh = reinterpret_cast<__half2*>(xw1out + (size_t)row * H1);
#pragma unroll
        for (int j = 0; j < H1 / 4; ++j) {
            oh[j * 2 + 0] = __floats2half2_rn(acc[j].x, acc[j].y);
            oh[j * 2 + 1] = __floats2half2_rn(acc[j].z, acc[j].w);
        }
        return;
    }

    // ------------- binning role: in-LDS bucket sort + coalesced out --------
    int2* sorted = bigbuf;

    int e0 = (blockIdx.x - GEMM_WGS) * CHUNK;
    int nhere = N_EDGES - e0; if (nhere > CHUNK) nhere = CHUNK;  // 4096 or 2560

    lcnt[threadIdx.x] = 0;
    __syncthreads();

    // load 16 edges/thread into regs + LDS histogram
    int   es[16];
    int   ed[16];
    float ew[16];
    {
        bool v = (threadIdx.x * 16) < nhere;         // nhere % 16 == 0
        int tb = e0 + threadIdx.x * 16;
        if (v) {
            const int4* sp = reinterpret_cast<const int4*>(src + tb);
            const int4* dp = reinterpret_cast<const int4*>(dst + tb);
            const float4* wp = reinterpret_cast<const float4*>(w + tb);
#pragma unroll
            for (int q = 0; q < 4; ++q) {
                int4 sv = sp[q], dv = dp[q]; float4 wv = wp[q];
                es[4*q+0]=sv.x; es[4*q+1]=sv.y; es[4*q+2]=sv.z; es[4*q+3]=sv.w;
                ed[4*q+0]=dv.x; ed[4*q+1]=dv.y; ed[4*q+2]=dv.z; ed[4*q+3]=dv.w;
                ew[4*q+0]=wv.x; ew[4*q+1]=wv.y; ew[4*q+2]=wv.z; ew[4*q+3]=wv.w;
            }
        } else {
#pragma unroll
            for (int k = 0; k < 16; ++k) { es[k]=0; ed[k]=-1; ew[k]=0.f; }
        }
    }
#pragma unroll
    for (int k = 0; k < 16; ++k)
        if (ed[k] >= 0) atomicAdd(&lcnt[ed[k] >> BSHIFT], 1);
    __syncthreads();

    // exclusive scan of the 256 counters (Hillis-Steele inclusive, then -v)
    int v = lcnt[threadIdx.x];
    lexcl[threadIdx.x] = v;
    __syncthreads();
    for (int off = 1; off < 256; off <<= 1) {
        int add = (threadIdx.x >= off) ? lexcl[threadIdx.x - off] : 0;
        __syncthreads();
        lexcl[threadIdx.x] += add;
        __syncthreads();
    }
    {
        int excl = lexcl[threadIdx.x] - v;
        lexcl[threadIdx.x] = excl;                   // now EXCLUSIVE prefix
        lcnt[threadIdx.x] = excl;                    // scatter cursors
        if (threadIdx.x < NBUCK)
            lbase[threadIdx.x] =
                (v > 0) ? atomicAdd(&cursor[threadIdx.x], v) : 0;
    }
    __syncthreads();

    // scatter records into LDS, sorted by bucket; remember run id per slot
#pragma unroll
    for (int k = 0; k < 16; ++k) {
        if (ed[k] >= 0) {
            int b = ed[k] >> BSHIFT;
            int p = atomicAdd(&lcnt[b], 1);
            sorted[p] = make_int2(
                es[k] | ((ed[k] & (BNODES - 1)) << 17), __float_as_int(ew[k]));
            rid[p] = (unsigned char)b;
        }
    }
    __syncthreads();

    // coalesced stream-out: consecutive j -> consecutive staging addresses
    // within each bucket run (~21 records), full-line stores.
    for (int j = threadIdx.x; j < nhere; j += 256) {
        int b = rid[j];
        int goff = lbase[b] + (j - lexcl[b]);
        if (goff < CAP)                               // capacity guard
            staging[b * CAP + goff] = sorted[j];
    }
}

// ---- sort_bucket: LDS counting sort -> csr + seg (4-aligned, 0-padded) ----
__global__ __launch_bounds__(1024) void sort_bucket(
    const int* __restrict__ cursor, const int2* __restrict__ staging,
    int2* __restrict__ csr, int2* __restrict__ seg)
{
    __shared__ int  lcnt[BNODES];                    // 2 KiB
    __shared__ int  lofs[BNODES];                    // 2 KiB
    __shared__ int2 sorted[CAP];                     // 80 KiB
    __shared__ int  total_sh;

    int b = blockIdx.x, t = threadIdx.x;
    int base = b * CAP;
    int cnt = cursor[b]; if (cnt > CAP) cnt = CAP;   // count (offset semantics)

    if (t < BNODES) lcnt[t] = 0;
    __syncthreads();

    for (int j = t; j < cnt; j += 1024)
        atomicAdd(&lcnt[(staging[base + j].x >> 17) & (BNODES - 1)], 1);
    __syncthreads();

    int v = (t < BNODES) ? lcnt[t] : 0;              // true count
    int pc = (v + 3) & ~3;                           // padded to multiple of 4
    if (t < BNODES) lofs[t] = pc;
    __syncthreads();
    for (int off = 1; off < BNODES; off <<= 1) {
        int add = (t >= off && t < BNODES) ? lofs[t - off] : 0;
        __syncthreads();
        if (t < BNODES) lofs[t] += add;
        __syncthreads();
    }
    if (t < BNODES) {
        int pexcl = lofs[t] - pc;                    // padded exclusive prefix
        seg[b * BNODES + t] = make_int2(base + pexcl, pc);
        lcnt[t] = pexcl;                             // running scatter cursors
        for (int j = v; j < pc; ++j)                 // zero-weight padding
            if (pexcl + j < CAP) sorted[pexcl + j] = make_int2(0, 0);
        if (t == BNODES - 1) {
            int tot = lofs[t]; if (tot > CAP) tot = CAP;
            total_sh = tot;
        }
    }
    __syncthreads();

    for (int j = t; j < cnt; j += 1024) {
        int2 c = staging[base + j];
        int node = (c.x >> 17) & (BNODES - 1);
        int pos = atomicAdd(&lcnt[node], 1);
        if (pos < CAP) sorted[pos] = make_int2(c.x & 0x1FFFF, c.y);
    }
    __syncthreads();

    int total = total_sh;
    for (int j = t; j < total; j += 1024) csr[base + j] = sorted[j];
}

// ---- layer1 SpMM + fused relu + W2: one wave per node, pipelined csr ------
__global__ __launch_bounds__(256) void spmm1_fused(
    const int2* __restrict__ seg, const int2* __restrict__ csr,
    const __half* __restrict__ xin, const float* __restrict__ W2,
    __half* __restrict__ h1w2h)
{
    int gid = blockIdx.x * 256 + threadIdx.x;        // grid covers N*64 exactly
    int node = __builtin_amdgcn_readfirstlane(gid >> 6);
    int f = gid & 63;
    int par = f >> 5;                                // edge parity
    int f2 = f & 31;                                 // feature pair: 2f2, 2f2+1

    // preload W2[par*32 .. +31][f2] into registers (cache-resident)
    float w2r[32];
#pragma unroll
    for (int kk = 0; kk < 32; ++kk)
        w2r[kk] = W2[(par * 32 + kk) * H2 + f2];

    int2 s = seg[node];
    int start = __builtin_amdgcn_readfirstlane(s.x);
    int cntp  = __builtin_amdgcn_readfirstlane(s.y); // multiple of 4
    const int4* csr4 = reinterpret_cast<const int4*>(csr);
    int iters = cntp >> 2;

    float2 a0 = make_float2(0.f, 0.f), a1 = make_float2(0.f, 0.f);
    // software pipeline: csr words for iter i+1 prefetched during iter i.
    int4 p0 = csr4[(start >> 1) + 0];
    int4 p1 = csr4[(start >> 1) + 1];
    for (int i = 0; i < iters; ++i) {
        int nb = (start >> 1) + (i + 1) * 2;
        int4 n0 = csr4[nb + 0];
        int4 n1 = csr4[nb + 1];
        int  sA = par ? p0.z : p0.x;
        float wA = __int_as_float(par ? p0.w : p0.y);
        int  sB = par ? p1.z : p1.x;
        float wB = __int_as_float(par ? p1.w : p1.y);
        float2 xA = __half22float2(
            *reinterpret_cast<const __half2*>(&xin[(size_t)sA * H1 + 2 * f2]));
        float2 xB = __half22float2(
            *reinterpret_cast<const __half2*>(&xin[(size_t)sB * H1 + 2 * f2]));
        a0.x += wA * xA.x; a0.y += wA * xA.y;
        a1.x += wB * xB.x; a1.y += wB * xB.y;
        p0 = n0; p1 = n1;
    }
    float rx = a0.x + a1.x, ry = a0.y + a1.y;
    rx += __shfl_xor(rx, 32, 64);                    // combine parities
    ry += __shfl_xor(ry, 32, 64);
    rx = fmaxf(rx, 0.f); ry = fmaxf(ry, 0.f);        // relu(h1) pair

    // o[j=f2] partial over k = par*32 + kk; pair p = 16*par + kk/2
    float o = 0.f;
#pragma unroll
    for (int kk = 0; kk < 32; kk += 2) {
        int p = 16 * par + (kk >> 1);
        o += __shfl(rx, p, 64) * w2r[kk];
        o += __shfl(ry, p, 64) * w2r[kk + 1];
    }
    o += __shfl_xor(o, 32, 64);
    if (f < 32)
        h1w2h[(size_t)node * H2 + f2] = __float2half(o);
}

// ---- layer 2 SpMM: wave per node, quarter-wave slots, pipelined csr -------
__global__ __launch_bounds__(256) void spmm_csr32h(
    const int2* __restrict__ seg, const int2* __restrict__ csr,
    const __half* __restrict__ xin, float* __restrict__ out)
{
    int gid = blockIdx.x * 256 + threadIdx.x;        // grid covers N*64 exactly
    int node = __builtin_amdgcn_readfirstlane(gid >> 6);
    int lane = gid & 63;
    int slot = lane >> 4;                            // edge slot 0..3
    int f2 = lane & 15;                              // feature pair: 2f2, 2f2+1

    int2 s = seg[node];
    int start = __builtin_amdgcn_readfirstlane(s.x);
    int cntp  = __builtin_amdgcn_readfirstlane(s.y); // multiple of 4
    const int4* csr4 = reinterpret_cast<const int4*>(csr);

    float2 a0 = make_float2(0.f, 0.f), a1 = make_float2(0.f, 0.f);
    int full = cntp >> 3;                            // 8-edge iterations
    int sb = start >> 1;
    int4 q0 = csr4[sb + 0], q1 = csr4[sb + 1];
    int4 q2 = csr4[sb + 2], q3 = csr4[sb + 3];
    for (int i = 0; i < full; ++i) {
        int nb = sb + (i + 1) * 4;
        int4 r0 = csr4[nb + 0], r1 = csr4[nb + 1];
        int4 r2 = csr4[nb + 2], r3 = csr4[nb + 3];
        int4 qa = (slot & 2) ? q1 : q0;
        int  sA = (slot & 1) ? qa.z : qa.x;
        float wA = __int_as_float((slot & 1) ? qa.w : qa.y);
        int4 qb = (slot & 2) ? q3 : q2;
        int  sB = (slot & 1) ? qb.z : qb.x;
        float wB = __int_as_float((slot & 1) ? qb.w : qb.y);
        float2 xA = __half22float2(
            *reinterpret_cast<const __half2*>(&xin[(size_t)sA * H2 + 2 * f2]));
        float2 xB = __half22float2(
            *reinterpret_cast<const __half2*>(&xin[(size_t)sB * H2 + 2 * f2]));
        a0.x += wA * xA.x; a0.y += wA * xA.y;
        a1.x += wB * xB.x; a1.y += wB * xB.y;
        q0 = r0; q1 = r1; q2 = r2; q3 = r3;
    }
    if (cntp & 4) {                                  // one 4-group tail
        int4 qa = (slot & 2) ? q1 : q0;              // q0,q1 already loaded
        int  sA = (slot & 1) ? qa.z : qa.x;
        float wA = __int_as_float((slot & 1) ? qa.w : qa.y);
        float2 xA = __half22float2(
            *reinterpret_cast<const __half2*>(&xin[(size_t)sA * H2 + 2 * f2]));
        a0.x += wA * xA.x; a0.y += wA * xA.y;
    }
    float ox = a0.x + a1.x, oy = a0.y + a1.y;
    ox += __shfl_xor(ox, 16, 64); oy += __shfl_xor(oy, 16, 64);
    ox += __shfl_xor(ox, 32, 64); oy += __shfl_xor(oy, 32, 64);
    if (lane < 16)
        *reinterpret_cast<float2*>(&out[(size_t)node * H2 + 2 * f2]) =
            make_float2(ox, oy);
}

extern "C" void kernel_launch(void* const* d_in, const int* in_sizes, int n_in,
                              void* d_out, int out_size, void* d_ws, size_t ws_size,
                              hipStream_t stream)
{
    const float* features    = (const float*)d_in[0];   // [N, 128]
    const float* edge_weight = (const float*)d_in[1];   // [E]
    const float* W1          = (const float*)d_in[2];   // [128, 64]
    const float* W2          = (const float*)d_in[3];   // [64, 32]
    const int*   src         = (const int*)d_in[4];     // [E]
    const int*   dst         = (const int*)d_in[5];     // [E]
    float* out = (float*)d_out;                          // [N, 32]

    // workspace layout (~52 MB)
    char* p = (char*)d_ws;
    __half* xw1h   = (__half*)p;    p += (size_t)N_NODES * H1 * 2;        // 12.8MB
    __half* h1w2h  = (__half*)p;    p += (size_t)N_NODES * H2 * 2;        // 6.4MB
    int2*  staging = (int2*)p;      p += (size_t)NBUCK * CAP * 8;         // 16.06MB
    int2*  csr     = (int2*)p;      p += (size_t)NBUCK * CAP * 8;         // 16.06MB
    int2*  seg     = (int2*)p;      p += (size_t)NBUCK * BNODES * 8;      // 0.80MB
    int*   cursor  = (int*)p;       p += 256 * 4;

    hipMemsetAsync(cursor, 0, 256 * 4, stream);      // cursor = in-bucket offsets
    pass1_bin_gemm1<<<P1_WGS + GEMM_WGS, 256, 0, stream>>>(
        src, dst, edge_weight, cursor, staging, features, W1, xw1h);
    sort_bucket<<<NBUCK, 1024, 0, stream>>>(cursor, staging, csr, seg);

    spmm1_fused<<<(N_NODES * 64) / 256, 256, 0, stream>>>(seg, csr, xw1h, W2, h1w2h);
    spmm_csr32h<<<(N_NODES * 64) / 256, 256, 0, stream>>>(seg, csr, h1w2h, out);
}